// Round 1
// baseline (2104.686 us; speedup 1.0000x reference)
//
#include <hip/hip_runtime.h>
#include <math.h>

#define PI_F 3.14159265358979f

// ================= Conv 3x3 (96->192) + pixel shuffle =================
// x: [8][96][128][128], wgt: [192][96][3][3]  ->  y: [8][48][256][256]
// oc = c*4 + r*2 + s maps to y[b][c][2h+r][2w+s].
#define OCB 8
#define ICB 2
#define PSTRIDE 67   // 66 used cols, padded

__global__ __launch_bounds__(256)
void conv_ps_kernel(const float* __restrict__ x, const float* __restrict__ wgt,
                    float* __restrict__ y) {
  __shared__ float wsh[OCB * 96 * 9];            // 6912 floats
  __shared__ float patch[ICB * 18 * PSTRIDE];    // 2*18*67
  const int tid  = threadIdx.x;
  const int bz   = blockIdx.z;
  const int b    = bz / 24;
  const int ocg  = bz % 24;
  const int row0 = blockIdx.y * 16;
  const int col0 = blockIdx.x * 64;
  const int tx   = tid & 15;    // 4-col group
  const int ty   = tid >> 4;    // row within tile

  for (int i = tid; i < OCB * 96 * 9; i += 256)
    wsh[i] = wgt[ocg * (OCB * 96 * 9) + i];

  float acc[OCB][4];
#pragma unroll
  for (int o = 0; o < OCB; ++o)
#pragma unroll
    for (int p = 0; p < 4; ++p) acc[o][p] = 0.f;

  const float* xb = x + (size_t)b * 96 * 128 * 128;

  for (int ic0 = 0; ic0 < 96; ic0 += ICB) {
    __syncthreads();
    // stage ICB channels of the (18 x 66) halo patch
    for (int idx = tid; idx < ICB * 18 * 66; idx += 256) {
      int j   = idx / (18 * 66);
      int rem = idx - j * (18 * 66);
      int r   = rem / 66;
      int c   = rem - r * 66;
      int gr  = row0 - 1 + r;
      int gc  = col0 - 1 + c;
      float v = 0.f;
      if ((unsigned)gr < 128u && (unsigned)gc < 128u)
        v = xb[((size_t)(ic0 + j) * 128 + gr) * 128 + gc];
      patch[j * (18 * PSTRIDE) + r * PSTRIDE + c] = v;
    }
    __syncthreads();
#pragma unroll
    for (int j = 0; j < ICB; ++j) {
      float xr[3][6];
      const float* pp = &patch[j * (18 * PSTRIDE) + ty * PSTRIDE + tx * 4];
#pragma unroll
      for (int dy = 0; dy < 3; ++dy)
#pragma unroll
        for (int dx = 0; dx < 6; ++dx)
          xr[dy][dx] = pp[dy * PSTRIDE + dx];
#pragma unroll
      for (int o = 0; o < OCB; ++o) {
        const float* wp = &wsh[(o * 96 + ic0 + j) * 9];
        float w0 = wp[0], w1 = wp[1], w2 = wp[2];
        float w3 = wp[3], w4 = wp[4], w5 = wp[5];
        float w6 = wp[6], w7 = wp[7], w8 = wp[8];
#pragma unroll
        for (int p = 0; p < 4; ++p) {
          acc[o][p] += w0 * xr[0][p] + w1 * xr[0][p + 1] + w2 * xr[0][p + 2]
                     + w3 * xr[1][p] + w4 * xr[1][p + 1] + w5 * xr[1][p + 2]
                     + w6 * xr[2][p] + w7 * xr[2][p + 1] + w8 * xr[2][p + 2];
        }
      }
    }
  }

  // epilogue: pixel-shuffled write
  const int h = row0 + ty;
#pragma unroll
  for (int o = 0; o < OCB; ++o) {
    int ocglob = ocg * OCB + o;
    int cq = ocglob >> 2;
    int r2 = (ocglob >> 1) & 1;
    int s2 = ocglob & 1;
    float* orow = y + (((size_t)b * 48 + cq) * 256 + (2 * h + r2)) * 256;
#pragma unroll
    for (int p = 0; p < 4; ++p) {
      int wpx = col0 + tx * 4 + p;
      orow[2 * wpx + s2] = acc[o][p];
    }
  }
}

// ================= 256-pt Stockham FFT -> mask -> IFFT =================
// mask keeps k in [0,64) u [192,256)  (i.e. shifted center crop [64:192)^2)
#define FS 260  // padded LDS line stride (float2 units)

__device__ __forceinline__ void fft_line(float2* A, float2* B, const float2* tw,
                                         int loff, int l, bool inv) {
  float2* S = A;
  float2* D = B;
#pragma unroll
  for (int t = 0; t < 8; ++t) {
    __syncthreads();
    const int m = 1 << t;
#pragma unroll
    for (int h = 0; h < 2; ++h) {
      int p = l + 64 * h;          // pair index in [0,128)
      int k = p & (m - 1);
      float2 a  = S[loff + p];
      float2 bb = S[loff + p + 128];
      float2 w  = tw[p - k];       // exp(-2*pi*i*(j<<t)/256)
      float wy  = inv ? -w.y : w.y;
      float dx = a.x - bb.x, dy = a.y - bb.y;
      D[loff + 2 * p - k]     = make_float2(a.x + bb.x, a.y + bb.y);
      D[loff + 2 * p - k + m] = make_float2(w.x * dx - wy * dy, w.x * dy + wy * dx);
    }
    float2* tmp = S; S = D; D = tmp;   // after 8 stages result is back in A
  }
  __syncthreads();
}

// Row pass: y (real) -> z1 = IFFT(mask*FFT(row)) complex, scaled 1/256.
__global__ __launch_bounds__(512)
void fft_rows_kernel(const float* __restrict__ y, float2* __restrict__ z1) {
  __shared__ float2 A[8 * FS], B[8 * FS], tw[128];
  const int tid = threadIdx.x;
  if (tid < 128) {
    float s, c;
    sincosf(-2.f * PI_F * (float)tid / 256.f, &s, &c);
    tw[tid] = make_float2(c, s);
  }
  const int line = tid >> 6, l = tid & 63;
  const int loff = line * FS;
  const size_t rowbase = ((size_t)blockIdx.x * 8 + line) * 256;
#pragma unroll
  for (int i = 0; i < 4; ++i) {
    int k = l + 64 * i;
    A[loff + k] = make_float2(y[rowbase + k], 0.f);
  }
  fft_line(A, B, tw, loff, l, false);
  A[loff + l + 64]  = make_float2(0.f, 0.f);   // zero k in [64,192)
  A[loff + l + 128] = make_float2(0.f, 0.f);
  fft_line(A, B, tw, loff, l, true);
#pragma unroll
  for (int i = 0; i < 4; ++i) {
    int k = l + 64 * i;
    float2 v = A[loff + k];
    z1[rowbase + k] = make_float2(v.x * (1.f / 256.f), v.y * (1.f / 256.f));
  }
}

// Col pass: z1 -> L = IFFT(mask*FFT(col))/256; out = beta*y + (1-2beta)*|L|
__global__ __launch_bounds__(512)
void fft_cols_kernel(const float2* __restrict__ z1, const float* __restrict__ y,
                     float* __restrict__ out, const float* __restrict__ betaPtr) {
  __shared__ float2 A[8 * FS], B[8 * FS], tw[128];
  const int tid = threadIdx.x;
  if (tid < 128) {
    float s, c;
    sincosf(-2.f * PI_F * (float)tid / 256.f, &s, &c);
    tw[tid] = make_float2(c, s);
  }
  const int img = blockIdx.x >> 5;
  const int c0  = (blockIdx.x & 31) * 8;
  const size_t ibase = (size_t)img * 65536;
  const int ci = tid & 7;       // column within 8-col strip
  const int r0 = tid >> 3;      // [0,64)
#pragma unroll
  for (int i = 0; i < 4; ++i) {
    int r = r0 + 64 * i;
    A[ci * FS + r] = z1[ibase + (size_t)r * 256 + c0 + ci];
  }
  const int line = tid >> 6, l = tid & 63;
  const int loff = line * FS;
  fft_line(A, B, tw, loff, l, false);
  A[loff + l + 64]  = make_float2(0.f, 0.f);
  A[loff + l + 128] = make_float2(0.f, 0.f);
  fft_line(A, B, tw, loff, l, true);
  const float beta = betaPtr[0];
  const float a1   = 1.f - 2.f * beta;
#pragma unroll
  for (int i = 0; i < 4; ++i) {
    int r = r0 + 64 * i;
    size_t gi = ibase + (size_t)r * 256 + c0 + ci;
    float2 v = A[ci * FS + r];
    float low = sqrtf(v.x * v.x + v.y * v.y) * (1.f / 256.f);
    out[gi] = beta * y[gi] + a1 * low;
  }
}

// ================= launch =================
extern "C" void kernel_launch(void* const* d_in, const int* in_sizes, int n_in,
                              void* d_out, int out_size, void* d_ws, size_t ws_size,
                              hipStream_t stream) {
  const float* x    = (const float*)d_in[0];
  const float* wgt  = (const float*)d_in[1];
  const float* beta = (const float*)d_in[2];
  float* out = (float*)d_out;    // holds y after conv, final result after col pass
  float2* z1 = (float2*)d_ws;

  dim3 cgrid(2, 8, 192);  // 128/64 cols, 128/16 rows, 8 batch * 24 oc-groups
  conv_ps_kernel<<<cgrid, 256, 0, stream>>>(x, wgt, out);

  const int NIMG = 8 * 48;                       // 384 images of 256x256
  const size_t per_img = 65536ull * sizeof(float2);
  int chunk = (int)(ws_size / per_img);
  if (chunk < 1) chunk = 1;
  if (chunk > NIMG) chunk = NIMG;
  for (int img0 = 0; img0 < NIMG; img0 += chunk) {
    int n = NIMG - img0;
    if (n > chunk) n = chunk;
    float* ych = out + (size_t)img0 * 65536;
    fft_rows_kernel<<<n * 32, 512, 0, stream>>>(ych, z1);
    fft_cols_kernel<<<n * 32, 512, 0, stream>>>(z1, ych, ych, beta);
  }
}

// Round 2
// 997.113 us; speedup vs baseline: 2.1108x; 2.1108x over previous
//
#include <hip/hip_runtime.h>
#include <math.h>

#define PI_F 3.14159265358979f

typedef __attribute__((ext_vector_type(8))) __bf16 bf16x8;
typedef __attribute__((ext_vector_type(4))) float f32x4;

__device__ __forceinline__ unsigned short f2bf_rne(float v) {
  union { float f; unsigned u; } c; c.f = v;
  unsigned u = c.u;
  return (unsigned short)((u + 0x7fffu + ((u >> 16) & 1u)) >> 16);
}
__device__ __forceinline__ float bfbits2f(unsigned short b) {
  union { unsigned u; float f; } c; c.u = ((unsigned)b) << 16; return c.f;
}

// ============ weight pre-split: w[oc][ic][3][3] -> whi/wlo[pos][oc][ic] ============
__global__ void prep_w(const float* __restrict__ w, unsigned short* __restrict__ whi,
                       unsigned short* __restrict__ wlo) {
  int i = blockIdx.x * 256 + threadIdx.x;   // (pos, oc*96+ic)
  if (i >= 9 * 192 * 96) return;
  int pos = i / (192 * 96);
  int rem = i - pos * (192 * 96);
  float v = w[(size_t)rem * 9 + pos];
  unsigned short h = f2bf_rne(v);
  whi[i] = h;
  wlo[i] = f2bf_rne(v - bfbits2f(h));
}

// ============ x pre-split per batch: NCHW fp32 -> padded NHWC bf16 hi/lo ============
// dest layout: [hp 0..129][wp 0..129][ic 0..95], hp=h+1, wp=w+1 (border stays 0)
__global__ __launch_bounds__(256)
void prep_x(const float* __restrict__ xb, unsigned short* __restrict__ xhi,
            unsigned short* __restrict__ xlo) {
  __shared__ float ld[64 * 33];
  const int w0 = blockIdx.x * 64, h = blockIdx.y, ic0 = blockIdx.z * 32;
  const int tid = threadIdx.x;
  const int wl = tid & 63, ics = tid >> 6;
#pragma unroll
  for (int it = 0; it < 8; ++it) {
    int icl = it * 4 + ics;
    ld[wl * 33 + icl] = xb[(size_t)(ic0 + icl) * 16384 + h * 128 + w0 + wl];
  }
  __syncthreads();
#pragma unroll
  for (int it = 0; it < 8; ++it) {
    int idx = it * 256 + tid;
    int wloc = idx >> 5, icl = idx & 31;
    float v = ld[wloc * 33 + icl];
    unsigned short hb = f2bf_rne(v);
    size_t dst = ((size_t)(h + 1) * 130 + (w0 + wloc + 1)) * 96 + ic0 + icl;
    xhi[dst] = hb;
    xlo[dst] = f2bf_rne(v - bfbits2f(hb));
  }
}

// ============ conv 3x3 as implicit GEMM, bf16 MFMA with hi/lo split ============
// block = 4 waves; each wave: M=64 oc x N=64 pixels; block tile M=64 x (2 rows x 128 w)
__global__ __launch_bounds__(256)
void conv_mfma(const unsigned short* __restrict__ xhi, const unsigned short* __restrict__ xlo,
               const unsigned short* __restrict__ whi, const unsigned short* __restrict__ wlo,
               float* __restrict__ y, int b) {
  const int tid  = threadIdx.x;
  const int wave = tid >> 6, lane = tid & 63;
  const int col  = lane & 15, quad = lane >> 4;
  const int mg   = blockIdx.x;              // oc base = 64*mg
  const int h    = 2 * blockIdx.y + (wave >> 1);
  const int w0   = (wave & 1) * 64;
  const int ocb  = mg * 64;

  f32x4 acc[4][4];
#pragma unroll
  for (int mt = 0; mt < 4; ++mt)
#pragma unroll
    for (int nt = 0; nt < 4; ++nt) acc[mt][nt] = (f32x4)0.f;

#pragma unroll
  for (int pos = 0; pos < 9; ++pos) {
    const int dy = pos / 3, dx = pos - 3 * (pos / 3);
    const size_t brow = ((size_t)(h + dy) * 130 + (w0 + dx)) * 96;
    const size_t arow = (size_t)pos * (192 * 96) + (size_t)ocb * 96;
#pragma unroll
    for (int icc = 0; icc < 96; icc += 32) {
      bf16x8 ah[4], al[4], bh[4], bl[4];
#pragma unroll
      for (int nt = 0; nt < 4; ++nt) {
        size_t o = brow + (size_t)(nt * 16 + col) * 96 + icc + quad * 8;
        bh[nt] = *(const bf16x8*)(xhi + o);
        bl[nt] = *(const bf16x8*)(xlo + o);
      }
#pragma unroll
      for (int mt = 0; mt < 4; ++mt) {
        size_t o = arow + (size_t)(mt * 16 + col) * 96 + icc + quad * 8;
        ah[mt] = *(const bf16x8*)(whi + o);
        al[mt] = *(const bf16x8*)(wlo + o);
      }
#pragma unroll
      for (int mt = 0; mt < 4; ++mt)
#pragma unroll
        for (int nt = 0; nt < 4; ++nt) {
          acc[mt][nt] = __builtin_amdgcn_mfma_f32_16x16x32_bf16(ah[mt], bh[nt], acc[mt][nt], 0, 0, 0);
          acc[mt][nt] = __builtin_amdgcn_mfma_f32_16x16x32_bf16(ah[mt], bl[nt], acc[mt][nt], 0, 0, 0);
          acc[mt][nt] = __builtin_amdgcn_mfma_f32_16x16x32_bf16(al[mt], bh[nt], acc[mt][nt], 0, 0, 0);
        }
    }
  }

  // epilogue: pixel-shuffled scatter.  D layout: m = quad*4+reg, n = col
  float* yb = y + (size_t)b * 48 * 256 * 256;
#pragma unroll
  for (int mt = 0; mt < 4; ++mt) {
#pragma unroll
    for (int r = 0; r < 4; ++r) {
      int oc = ocb + mt * 16 + quad * 4 + r;
      int cq = oc >> 2, r2 = (oc >> 1) & 1, s2 = oc & 1;
      float* orow = yb + ((size_t)cq * 256 + 2 * h + r2) * 256;
#pragma unroll
      for (int nt = 0; nt < 4; ++nt) {
        int w = w0 + nt * 16 + col;
        orow[2 * w + s2] = acc[mt][nt][r];
      }
    }
  }
}

// ============ fallback fp32 conv (used only if ws is too small) ============
#define OCB 8
#define ICB 2
#define PSTRIDE 67

__global__ __launch_bounds__(256)
void conv_ps_kernel(const float* __restrict__ x, const float* __restrict__ wgt,
                    float* __restrict__ y) {
  __shared__ float wsh[OCB * 96 * 9];
  __shared__ float patch[ICB * 18 * PSTRIDE];
  const int tid = threadIdx.x;
  const int bz = blockIdx.z;
  const int b = bz / 24;
  const int ocg = bz % 24;
  const int row0 = blockIdx.y * 16;
  const int col0 = blockIdx.x * 64;
  const int tx = tid & 15;
  const int ty = tid >> 4;
  for (int i = tid; i < OCB * 96 * 9; i += 256)
    wsh[i] = wgt[ocg * (OCB * 96 * 9) + i];
  float acc[OCB][4];
#pragma unroll
  for (int o = 0; o < OCB; ++o)
#pragma unroll
    for (int p = 0; p < 4; ++p) acc[o][p] = 0.f;
  const float* xb = x + (size_t)b * 96 * 128 * 128;
  for (int ic0 = 0; ic0 < 96; ic0 += ICB) {
    __syncthreads();
    for (int idx = tid; idx < ICB * 18 * 66; idx += 256) {
      int j = idx / (18 * 66);
      int rem = idx - j * (18 * 66);
      int r = rem / 66;
      int c = rem - r * 66;
      int gr = row0 - 1 + r;
      int gc = col0 - 1 + c;
      float v = 0.f;
      if ((unsigned)gr < 128u && (unsigned)gc < 128u)
        v = xb[((size_t)(ic0 + j) * 128 + gr) * 128 + gc];
      patch[j * (18 * PSTRIDE) + r * PSTRIDE + c] = v;
    }
    __syncthreads();
#pragma unroll
    for (int j = 0; j < ICB; ++j) {
      float xr[3][6];
      const float* pp = &patch[j * (18 * PSTRIDE) + ty * PSTRIDE + tx * 4];
#pragma unroll
      for (int dy = 0; dy < 3; ++dy)
#pragma unroll
        for (int dx = 0; dx < 6; ++dx) xr[dy][dx] = pp[dy * PSTRIDE + dx];
#pragma unroll
      for (int o = 0; o < OCB; ++o) {
        const float* wp = &wsh[(o * 96 + ic0 + j) * 9];
        float w0 = wp[0], w1 = wp[1], w2 = wp[2], w3 = wp[3], w4 = wp[4];
        float w5 = wp[5], w6 = wp[6], w7 = wp[7], w8 = wp[8];
#pragma unroll
        for (int p = 0; p < 4; ++p)
          acc[o][p] += w0 * xr[0][p] + w1 * xr[0][p + 1] + w2 * xr[0][p + 2]
                     + w3 * xr[1][p] + w4 * xr[1][p + 1] + w5 * xr[1][p + 2]
                     + w6 * xr[2][p] + w7 * xr[2][p + 1] + w8 * xr[2][p + 2];
      }
    }
  }
  const int h = row0 + ty;
#pragma unroll
  for (int o = 0; o < OCB; ++o) {
    int ocglob = ocg * OCB + o;
    int cq = ocglob >> 2;
    int r2 = (ocglob >> 1) & 1;
    int s2 = ocglob & 1;
    float* orow = y + (((size_t)b * 48 + cq) * 256 + (2 * h + r2)) * 256;
#pragma unroll
    for (int p = 0; p < 4; ++p) orow[2 * (col0 + tx * 4 + p) + s2] = acc[o][p];
  }
}

// ================= 256-pt Stockham FFT -> mask -> IFFT =================
#define FS 260

__device__ __forceinline__ void fft_line(float2* A, float2* B, const float2* tw,
                                         int loff, int l, bool inv) {
  float2* S = A;
  float2* D = B;
#pragma unroll
  for (int t = 0; t < 8; ++t) {
    __syncthreads();
    const int m = 1 << t;
#pragma unroll
    for (int hh = 0; hh < 2; ++hh) {
      int p = l + 64 * hh;
      int k = p & (m - 1);
      float2 a = S[loff + p];
      float2 bb = S[loff + p + 128];
      float2 w = tw[p - k];
      float wy = inv ? -w.y : w.y;
      float dx = a.x - bb.x, dy = a.y - bb.y;
      D[loff + 2 * p - k] = make_float2(a.x + bb.x, a.y + bb.y);
      D[loff + 2 * p - k + m] = make_float2(w.x * dx - wy * dy, w.x * dy + wy * dx);
    }
    float2* tmp = S; S = D; D = tmp;
  }
  __syncthreads();
}

__global__ __launch_bounds__(512)
void fft_rows_kernel(const float* __restrict__ y, float2* __restrict__ z1) {
  __shared__ float2 A[8 * FS], B[8 * FS], tw[128];
  const int tid = threadIdx.x;
  if (tid < 128) {
    float s, c;
    sincosf(-2.f * PI_F * (float)tid / 256.f, &s, &c);
    tw[tid] = make_float2(c, s);
  }
  const int line = tid >> 6, l = tid & 63;
  const int loff = line * FS;
  const size_t rowbase = ((size_t)blockIdx.x * 8 + line) * 256;
#pragma unroll
  for (int i = 0; i < 4; ++i) {
    int k = l + 64 * i;
    A[loff + k] = make_float2(y[rowbase + k], 0.f);
  }
  fft_line(A, B, tw, loff, l, false);
  A[loff + l + 64] = make_float2(0.f, 0.f);
  A[loff + l + 128] = make_float2(0.f, 0.f);
  fft_line(A, B, tw, loff, l, true);
#pragma unroll
  for (int i = 0; i < 4; ++i) {
    int k = l + 64 * i;
    float2 v = A[loff + k];
    z1[rowbase + k] = make_float2(v.x * (1.f / 256.f), v.y * (1.f / 256.f));
  }
}

__global__ __launch_bounds__(512)
void fft_cols_kernel(const float2* __restrict__ z1, const float* __restrict__ y,
                     float* __restrict__ out, const float* __restrict__ betaPtr) {
  __shared__ float2 A[8 * FS], B[8 * FS], tw[128];
  const int tid = threadIdx.x;
  if (tid < 128) {
    float s, c;
    sincosf(-2.f * PI_F * (float)tid / 256.f, &s, &c);
    tw[tid] = make_float2(c, s);
  }
  const int img = blockIdx.x >> 5;
  const int c0 = (blockIdx.x & 31) * 8;
  const size_t ibase = (size_t)img * 65536;
  const int ci = tid & 7;
  const int r0 = tid >> 3;
#pragma unroll
  for (int i = 0; i < 4; ++i) {
    int r = r0 + 64 * i;
    A[ci * FS + r] = z1[ibase + (size_t)r * 256 + c0 + ci];
  }
  const int line = tid >> 6, l = tid & 63;
  const int loff = line * FS;
  fft_line(A, B, tw, loff, l, false);
  A[loff + l + 64] = make_float2(0.f, 0.f);
  A[loff + l + 128] = make_float2(0.f, 0.f);
  fft_line(A, B, tw, loff, l, true);
  const float beta = betaPtr[0];
  const float a1 = 1.f - 2.f * beta;
#pragma unroll
  for (int i = 0; i < 4; ++i) {
    int r = r0 + 64 * i;
    size_t gi = ibase + (size_t)r * 256 + c0 + ci;
    float2 v = A[ci * FS + r];
    float low = sqrtf(v.x * v.x + v.y * v.y) * (1.f / 256.f);
    out[gi] = beta * y[gi] + a1 * low;
  }
}

// ================= launch =================
extern "C" void kernel_launch(void* const* d_in, const int* in_sizes, int n_in,
                              void* d_out, int out_size, void* d_ws, size_t ws_size,
                              hipStream_t stream) {
  const float* x = (const float*)d_in[0];
  const float* wgt = (const float*)d_in[1];
  const float* beta = (const float*)d_in[2];
  float* out = (float*)d_out;

  const size_t xplane = (size_t)130 * 130 * 96;          // per-batch padded NHWC plane (elems)
  const size_t wplane = (size_t)9 * 192 * 96;            // weight plane (elems)
  const size_t head = (2 * xplane + 2 * wplane) * sizeof(unsigned short);
  const size_t per_img = 65536ull * sizeof(float2);
  const int NIMG = 8 * 48;

  float2* z1;
  size_t z1_bytes;

  if (ws_size >= head + per_img) {
    // -------- MFMA path --------
    unsigned short* xhi = (unsigned short*)d_ws;
    unsigned short* xlo = xhi + xplane;
    unsigned short* whi = xlo + xplane;
    unsigned short* wlo = whi + wplane;
    z1 = (float2*)((char*)d_ws + head);
    z1_bytes = ws_size - head;

    hipMemsetAsync(d_ws, 0, 2 * xplane * sizeof(unsigned short), stream);
    prep_w<<<(9 * 192 * 96 + 255) / 256, 256, 0, stream>>>(wgt, whi, wlo);
    for (int b = 0; b < 8; ++b) {
      prep_x<<<dim3(2, 128, 3), 256, 0, stream>>>(x + (size_t)b * 96 * 128 * 128, xhi, xlo);
      conv_mfma<<<dim3(3, 64), 256, 0, stream>>>(xhi, xlo, whi, wlo, out, b);
    }
  } else {
    // -------- fallback fp32 path --------
    z1 = (float2*)d_ws;
    z1_bytes = ws_size;
    dim3 cgrid(2, 8, 192);
    conv_ps_kernel<<<cgrid, 256, 0, stream>>>(x, wgt, out);
  }

  int chunk = (int)(z1_bytes / per_img);
  if (chunk < 1) chunk = 1;
  if (chunk > NIMG) chunk = NIMG;
  for (int img0 = 0; img0 < NIMG; img0 += chunk) {
    int n = NIMG - img0;
    if (n > chunk) n = chunk;
    float* ych = out + (size_t)img0 * 65536;
    fft_rows_kernel<<<n * 32, 512, 0, stream>>>(ych, z1);
    fft_cols_kernel<<<n * 32, 512, 0, stream>>>(z1, ych, ych, beta);
  }
}

// Round 3
// 647.067 us; speedup vs baseline: 3.2527x; 1.5410x over previous
//
#include <hip/hip_runtime.h>
#include <math.h>

#define PI_F 3.14159265358979f

typedef __attribute__((ext_vector_type(8))) __bf16 bf16x8;
typedef __attribute__((ext_vector_type(4))) float f32x4;

__device__ __forceinline__ unsigned short f2bf_rne(float v) {
  union { float f; unsigned u; } c; c.f = v;
  unsigned u = c.u;
  return (unsigned short)((u + 0x7fffu + ((u >> 16) & 1u)) >> 16);
}
__device__ __forceinline__ float bfbits2f(unsigned short b) {
  union { unsigned u; float f; } c; c.u = ((unsigned)b) << 16; return c.f;
}

// ============ weight pre-split: w[oc][ic][3][3] -> whi/wlo[pos][oc][ic] ============
__global__ void prep_w(const float* __restrict__ w, unsigned short* __restrict__ whi,
                       unsigned short* __restrict__ wlo) {
  int i = blockIdx.x * 256 + threadIdx.x;
  if (i >= 9 * 192 * 96) return;
  int pos = i / (192 * 96);
  int rem = i - pos * (192 * 96);
  float v = w[(size_t)rem * 9 + pos];
  unsigned short h = f2bf_rne(v);
  whi[i] = h;
  wlo[i] = f2bf_rne(v - bfbits2f(h));
}

// ============ conv 3x3 implicit GEMM, fused x->bf16 staging in LDS ============
// block: 256 thr, tile = 1 row x 64 w x 192 oc; wave handles 48 oc x 64 px.
#define ICP 104  // padded ic stride (bytes stride 208: 16B-aligned, 2-way-ish banks)

__global__ __launch_bounds__(256)
void conv_mfma(const float* __restrict__ x,
               const unsigned short* __restrict__ whi, const unsigned short* __restrict__ wlo,
               float* __restrict__ y) {
  __shared__ unsigned short patch[3 * 66 * ICP];   // 41184 B
  const int tid  = threadIdx.x;
  const int wave = tid >> 6, lane = tid & 63;
  const int col  = lane & 15, quad = lane >> 4;
  const int w0 = blockIdx.x * 64;
  const int h  = blockIdx.y;
  const int b  = blockIdx.z;
  const float* xb = x + (size_t)b * 96 * 128 * 128;

  // stage 3-row halo patch, fp32 -> bf16
  for (int i = tid; i < 3 * 66 * 96; i += 256) {
    int w  = i % 66;
    int t  = i / 66;
    int r  = t % 3;
    int ic = t / 3;
    int gr = h - 1 + r, gc = w0 - 1 + w;
    float v = 0.f;
    if ((unsigned)gr < 128u && (unsigned)gc < 128u)
      v = xb[(size_t)ic * 16384 + gr * 128 + gc];
    patch[(r * 66 + w) * ICP + ic] = f2bf_rne(v);
  }
  __syncthreads();

  f32x4 acc[3][4];
#pragma unroll
  for (int mt = 0; mt < 3; ++mt)
#pragma unroll
    for (int nt = 0; nt < 4; ++nt) acc[mt][nt] = (f32x4)0.f;

  for (int pos = 0; pos < 9; ++pos) {
    const int dy = pos / 3, dx = pos - 3 * (pos / 3);
#pragma unroll
    for (int icc = 0; icc < 96; icc += 32) {
      bf16x8 bfrag[4];
#pragma unroll
      for (int nt = 0; nt < 4; ++nt) {
        int px = nt * 16 + col;
        bfrag[nt] = *(const bf16x8*)&patch[(dy * 66 + px + dx) * ICP + icc + quad * 8];
      }
#pragma unroll
      for (int mt = 0; mt < 3; ++mt) {
        int oc = 48 * wave + mt * 16 + col;
        size_t o = (size_t)pos * 18432 + (size_t)oc * 96 + icc + quad * 8;
        bf16x8 ah = *(const bf16x8*)(whi + o);
        bf16x8 al = *(const bf16x8*)(wlo + o);
#pragma unroll
        for (int nt = 0; nt < 4; ++nt) {
          acc[mt][nt] = __builtin_amdgcn_mfma_f32_16x16x32_bf16(ah, bfrag[nt], acc[mt][nt], 0, 0, 0);
          acc[mt][nt] = __builtin_amdgcn_mfma_f32_16x16x32_bf16(al, bfrag[nt], acc[mt][nt], 0, 0, 0);
        }
      }
    }
  }

  // epilogue: pixel-shuffled scatter.  D layout: m = quad*4+reg, n = col
  float* yb = y + (size_t)b * 48 * 65536;
#pragma unroll
  for (int mt = 0; mt < 3; ++mt) {
#pragma unroll
    for (int r = 0; r < 4; ++r) {
      int oc = 48 * wave + mt * 16 + quad * 4 + r;
      int cq = oc >> 2, r2 = (oc >> 1) & 1, s2 = oc & 1;
      float* orow = yb + ((size_t)cq * 256 + 2 * h + r2) * 256;
#pragma unroll
      for (int nt = 0; nt < 4; ++nt) {
        int w = w0 + nt * 16 + col;
        orow[2 * w + s2] = acc[mt][nt][r];
      }
    }
  }
}

// ============ fallback fp32 conv (only if ws can't hold weights) ============
#define OCB 8
#define ICB 2
#define PSTRIDE 67
__global__ __launch_bounds__(256)
void conv_ps_kernel(const float* __restrict__ x, const float* __restrict__ wgt,
                    float* __restrict__ y) {
  __shared__ float wsh[OCB * 96 * 9];
  __shared__ float patch[ICB * 18 * PSTRIDE];
  const int tid = threadIdx.x;
  const int b = blockIdx.z / 24, ocg = blockIdx.z % 24;
  const int row0 = blockIdx.y * 16, col0 = blockIdx.x * 64;
  const int tx = tid & 15, ty = tid >> 4;
  for (int i = tid; i < OCB * 96 * 9; i += 256) wsh[i] = wgt[ocg * (OCB * 96 * 9) + i];
  float acc[OCB][4];
#pragma unroll
  for (int o = 0; o < OCB; ++o)
#pragma unroll
    for (int p = 0; p < 4; ++p) acc[o][p] = 0.f;
  const float* xb = x + (size_t)b * 96 * 128 * 128;
  for (int ic0 = 0; ic0 < 96; ic0 += ICB) {
    __syncthreads();
    for (int idx = tid; idx < ICB * 18 * 66; idx += 256) {
      int j = idx / (18 * 66), rem = idx - j * (18 * 66);
      int r = rem / 66, c = rem - r * 66;
      int gr = row0 - 1 + r, gc = col0 - 1 + c;
      float v = 0.f;
      if ((unsigned)gr < 128u && (unsigned)gc < 128u)
        v = xb[((size_t)(ic0 + j) * 128 + gr) * 128 + gc];
      patch[j * (18 * PSTRIDE) + r * PSTRIDE + c] = v;
    }
    __syncthreads();
#pragma unroll
    for (int j = 0; j < ICB; ++j) {
      float xr[3][6];
      const float* pp = &patch[j * (18 * PSTRIDE) + ty * PSTRIDE + tx * 4];
#pragma unroll
      for (int dy = 0; dy < 3; ++dy)
#pragma unroll
        for (int dx = 0; dx < 6; ++dx) xr[dy][dx] = pp[dy * PSTRIDE + dx];
#pragma unroll
      for (int o = 0; o < OCB; ++o) {
        const float* wp = &wsh[(o * 96 + ic0 + j) * 9];
#pragma unroll
        for (int p = 0; p < 4; ++p)
          acc[o][p] += wp[0] * xr[0][p] + wp[1] * xr[0][p + 1] + wp[2] * xr[0][p + 2]
                     + wp[3] * xr[1][p] + wp[4] * xr[1][p + 1] + wp[5] * xr[1][p + 2]
                     + wp[6] * xr[2][p] + wp[7] * xr[2][p + 1] + wp[8] * xr[2][p + 2];
      }
    }
  }
  const int h = row0 + ty;
#pragma unroll
  for (int o = 0; o < OCB; ++o) {
    int ocglob = ocg * OCB + o;
    int cq = ocglob >> 2, r2 = (ocglob >> 1) & 1, s2 = ocglob & 1;
    float* orow = y + (((size_t)b * 48 + cq) * 256 + (2 * h + r2)) * 256;
#pragma unroll
    for (int p = 0; p < 4; ++p) orow[2 * (col0 + tx * 4 + p) + s2] = acc[o][p];
  }
}

// ================= in-place DIF forward / DIT inverse, no bit-reversal =================
// mask (zero k in [64,192)) in DIF (bit-reversed) order is:  j & 3 in {1,2}
#define FS 261

template <int NT>
__device__ __forceinline__ void dif_fft(float2* S, const float2* tw, int loff, int l) {
#pragma unroll
  for (int s = 0; s < 8; ++s) {
    const int m = 128 >> s;
    __syncthreads();
#pragma unroll
    for (int hh = 0; hh < 128 / NT; ++hh) {
      int q = l + NT * hh;
      int k = q & (m - 1);
      int i = loff + 2 * q - k;
      float2 a = S[i], b = S[i + m];
      float2 w = tw[k << s];
      S[i] = make_float2(a.x + b.x, a.y + b.y);
      float dx = a.x - b.x, dy = a.y - b.y;
      S[i + m] = make_float2(dx * w.x - dy * w.y, dx * w.y + dy * w.x);
    }
  }
  __syncthreads();
}

template <int NT>
__device__ __forceinline__ void dit_ifft(float2* S, const float2* tw, int loff, int l) {
#pragma unroll
  for (int s = 7; s >= 0; --s) {
    const int m = 128 >> s;
    __syncthreads();
#pragma unroll
    for (int hh = 0; hh < 128 / NT; ++hh) {
      int q = l + NT * hh;
      int k = q & (m - 1);
      int i = loff + 2 * q - k;
      float2 a = S[i], b = S[i + m];
      float2 w = tw[k << s];                 // use conj(w)
      float bx = b.x * w.x + b.y * w.y;
      float by = b.y * w.x - b.x * w.y;
      S[i]     = make_float2(a.x + bx, a.y + by);
      S[i + m] = make_float2(a.x - bx, a.y - by);
    }
  }
  __syncthreads();
}

// Row pass: y (real) -> z1 = IFFT(mask*FFT(row))/256, 8 rows/block, 512 thr
__global__ __launch_bounds__(512)
void fft_rows_kernel(const float* __restrict__ y, float2* __restrict__ z1) {
  __shared__ float2 A[8 * FS];
  __shared__ float2 tw[128];
  const int tid = threadIdx.x;
  if (tid < 128) {
    float s, c;
    sincosf(-2.f * PI_F * (float)tid / 256.f, &s, &c);
    tw[tid] = make_float2(c, s);
  }
  const int line = tid >> 6, l = tid & 63;
  const int loff = line * FS;
  const size_t rowbase = ((size_t)blockIdx.x * 8 + line) * 256;
#pragma unroll
  for (int i = 0; i < 4; ++i) {
    int k = l + 64 * i;
    A[loff + k] = make_float2(y[rowbase + k], 0.f);
  }
  dif_fft<64>(A, tw, loff, l);
  A[loff + 4 * l + 1] = make_float2(0.f, 0.f);
  A[loff + 4 * l + 2] = make_float2(0.f, 0.f);
  dit_ifft<64>(A, tw, loff, l);
#pragma unroll
  for (int i = 0; i < 4; ++i) {
    int k = l + 64 * i;
    float2 v = A[loff + k];
    z1[rowbase + k] = make_float2(v.x * (1.f / 256.f), v.y * (1.f / 256.f));
  }
}

// Col pass: 16-col strips (128B lines), 512 thr, 16 lines
__global__ __launch_bounds__(512)
void fft_cols_kernel(const float2* __restrict__ z1, const float* __restrict__ yy,
                     float* __restrict__ out, const float* __restrict__ betaPtr) {
  __shared__ float2 A[16 * FS];
  __shared__ float2 tw[128];
  const int tid = threadIdx.x;
  if (tid < 128) {
    float s, c;
    sincosf(-2.f * PI_F * (float)tid / 256.f, &s, &c);
    tw[tid] = make_float2(c, s);
  }
  const int img = blockIdx.x >> 4;
  const int c0  = (blockIdx.x & 15) * 16;
  const size_t ibase = (size_t)img * 65536;
  const int ci = tid & 15, rr = tid >> 4;   // load/store mapping: 16 lanes = 128 B
#pragma unroll
  for (int i = 0; i < 8; ++i) {
    int r = rr + 32 * i;
    A[ci * FS + r] = z1[ibase + (size_t)r * 256 + c0 + ci];
  }
  const int line = tid >> 5, l = tid & 31;
  const int loff = line * FS;
  dif_fft<32>(A, tw, loff, l);
#pragma unroll
  for (int hh = 0; hh < 2; ++hh) {
    int t = l + 32 * hh;
    A[loff + 4 * t + 1] = make_float2(0.f, 0.f);
    A[loff + 4 * t + 2] = make_float2(0.f, 0.f);
  }
  dit_ifft<32>(A, tw, loff, l);
  const float beta = betaPtr[0];
  const float a1 = 1.f - 2.f * beta;
#pragma unroll
  for (int i = 0; i < 8; ++i) {
    int r = rr + 32 * i;
    size_t gi = ibase + (size_t)r * 256 + c0 + ci;
    float2 v = A[ci * FS + r];
    float low = sqrtf(v.x * v.x + v.y * v.y) * (1.f / 256.f);
    out[gi] = beta * yy[gi] + a1 * low;
  }
}

// ================= launch =================
extern "C" void kernel_launch(void* const* d_in, const int* in_sizes, int n_in,
                              void* d_out, int out_size, void* d_ws, size_t ws_size,
                              hipStream_t stream) {
  const float* x = (const float*)d_in[0];
  const float* wgt = (const float*)d_in[1];
  const float* beta = (const float*)d_in[2];
  float* out = (float*)d_out;

  const size_t wplane = (size_t)9 * 192 * 96;
  const size_t wbytes = (2 * wplane * sizeof(unsigned short) + 255) & ~(size_t)255;
  const size_t per_img = 65536ull * sizeof(float2);
  const int NIMG = 8 * 48;

  float2* z1;
  size_t z1_bytes;

  if (ws_size >= wbytes + per_img) {
    unsigned short* whi = (unsigned short*)d_ws;
    unsigned short* wlo = whi + wplane;
    z1 = (float2*)((char*)d_ws + wbytes);
    z1_bytes = ws_size - wbytes;
    prep_w<<<648, 256, 0, stream>>>(wgt, whi, wlo);
    conv_mfma<<<dim3(2, 128, 8), 256, 0, stream>>>(x, whi, wlo, out);
  } else {
    z1 = (float2*)d_ws;
    z1_bytes = ws_size;
    conv_ps_kernel<<<dim3(2, 8, 192), 256, 0, stream>>>(x, wgt, out);
  }

  int chunk = (int)(z1_bytes / per_img);
  if (chunk < 1) chunk = 1;
  if (chunk > NIMG) chunk = NIMG;
  for (int img0 = 0; img0 < NIMG; img0 += chunk) {
    int n = NIMG - img0;
    if (n > chunk) n = chunk;
    float* ych = out + (size_t)img0 * 65536;
    fft_rows_kernel<<<n * 32, 512, 0, stream>>>(ych, z1);
    fft_cols_kernel<<<n * 16, 512, 0, stream>>>(z1, ych, ych, beta);
  }
}

// Round 4
// 442.812 us; speedup vs baseline: 4.7530x; 1.4613x over previous
//
#include <hip/hip_runtime.h>
#include <math.h>

#define PI_F 3.14159265358979f

typedef __attribute__((ext_vector_type(8))) __bf16 bf16x8;
typedef __attribute__((ext_vector_type(4))) float f32x4;

__device__ __forceinline__ unsigned short f2bf_rne(float v) {
  union { float f; unsigned u; } c; c.f = v;
  unsigned u = c.u;
  return (unsigned short)((u + 0x7fffu + ((u >> 16) & 1u)) >> 16);
}
__device__ __forceinline__ float bfbits2f(unsigned short b) {
  union { unsigned u; float f; } c; c.u = ((unsigned)b) << 16; return c.f;
}

// ============ weight pre-split: w[oc][ic][3][3] -> whi/wlo[pos][oc][ic] ============
__global__ void prep_w(const float* __restrict__ w, unsigned short* __restrict__ whi,
                       unsigned short* __restrict__ wlo) {
  int i = blockIdx.x * 256 + threadIdx.x;
  if (i >= 9 * 192 * 96) return;
  int pos = i / (192 * 96);
  int rem = i - pos * (192 * 96);
  float v = w[(size_t)rem * 9 + pos];
  unsigned short h = f2bf_rne(v);
  whi[i] = h;
  wlo[i] = f2bf_rne(v - bfbits2f(h));
}

// ============ conv 3x3 implicit GEMM, fused x->bf16 staging in LDS ============
#define ICP 104

__global__ __launch_bounds__(256)
void conv_mfma(const float* __restrict__ x,
               const unsigned short* __restrict__ whi, const unsigned short* __restrict__ wlo,
               float* __restrict__ y) {
  __shared__ unsigned short patch[3 * 66 * ICP];
  const int tid  = threadIdx.x;
  const int wave = tid >> 6, lane = tid & 63;
  const int col  = lane & 15, quad = lane >> 4;
  const int w0 = blockIdx.x * 64;
  const int h  = blockIdx.y;
  const int b  = blockIdx.z;
  const float* xb = x + (size_t)b * 96 * 128 * 128;

  // vectorized staging: 288 (ic,r) pairs, 16 pairs/iter, float4 main + 2-lane halo
  {
    const int l16 = tid & 15;
    const int pg  = tid >> 4;
#pragma unroll
    for (int it = 0; it < 18; ++it) {
      int pp = it * 16 + pg;
      int r  = pp % 3;
      int ic = pp / 3;
      int gr = h - 1 + r;
      const float* rowp = xb + (size_t)ic * 16384 + gr * 128;
      float4 v = make_float4(0.f, 0.f, 0.f, 0.f);
      if ((unsigned)gr < 128u) v = *(const float4*)(rowp + w0 + 4 * l16);
      unsigned short* pb = &patch[(r * 66 + 1 + 4 * l16) * ICP + ic];
      pb[0]       = f2bf_rne(v.x);
      pb[ICP]     = f2bf_rne(v.y);
      pb[2 * ICP] = f2bf_rne(v.z);
      pb[3 * ICP] = f2bf_rne(v.w);
      if (l16 < 2) {
        int gc = (l16 == 0) ? (w0 - 1) : (w0 + 64);
        float hv = 0.f;
        if ((unsigned)gr < 128u && (unsigned)gc < 128u) hv = rowp[gc];
        patch[(r * 66 + (l16 == 0 ? 0 : 65)) * ICP + ic] = f2bf_rne(hv);
      }
    }
  }
  __syncthreads();

  f32x4 acc[3][4];
#pragma unroll
  for (int mt = 0; mt < 3; ++mt)
#pragma unroll
    for (int nt = 0; nt < 4; ++nt) acc[mt][nt] = (f32x4)0.f;

  for (int pos = 0; pos < 9; ++pos) {
    const int dy = pos / 3, dx = pos - 3 * (pos / 3);
#pragma unroll
    for (int icc = 0; icc < 96; icc += 32) {
      bf16x8 bfrag[4];
#pragma unroll
      for (int nt = 0; nt < 4; ++nt) {
        int px = nt * 16 + col;
        bfrag[nt] = *(const bf16x8*)&patch[(dy * 66 + px + dx) * ICP + icc + quad * 8];
      }
#pragma unroll
      for (int mt = 0; mt < 3; ++mt) {
        int oc = 48 * wave + mt * 16 + col;
        size_t o = (size_t)pos * 18432 + (size_t)oc * 96 + icc + quad * 8;
        bf16x8 ah = *(const bf16x8*)(whi + o);
        bf16x8 al = *(const bf16x8*)(wlo + o);
#pragma unroll
        for (int nt = 0; nt < 4; ++nt) {
          acc[mt][nt] = __builtin_amdgcn_mfma_f32_16x16x32_bf16(ah, bfrag[nt], acc[mt][nt], 0, 0, 0);
          acc[mt][nt] = __builtin_amdgcn_mfma_f32_16x16x32_bf16(al, bfrag[nt], acc[mt][nt], 0, 0, 0);
        }
      }
    }
  }

  float* yb = y + (size_t)b * 48 * 65536;
#pragma unroll
  for (int mt = 0; mt < 3; ++mt) {
#pragma unroll
    for (int r = 0; r < 4; ++r) {
      int oc = 48 * wave + mt * 16 + quad * 4 + r;
      int cq = oc >> 2, r2 = (oc >> 1) & 1, s2 = oc & 1;
      float* orow = yb + ((size_t)cq * 256 + 2 * h + r2) * 256;
#pragma unroll
      for (int nt = 0; nt < 4; ++nt) {
        int w = w0 + nt * 16 + col;
        orow[2 * w + s2] = acc[mt][nt][r];
      }
    }
  }
}

// ============ fallback fp32 conv ============
#define OCB 8
#define ICB 2
#define PSTRIDE 67
__global__ __launch_bounds__(256)
void conv_ps_kernel(const float* __restrict__ x, const float* __restrict__ wgt,
                    float* __restrict__ y) {
  __shared__ float wsh[OCB * 96 * 9];
  __shared__ float patch[ICB * 18 * PSTRIDE];
  const int tid = threadIdx.x;
  const int b = blockIdx.z / 24, ocg = blockIdx.z % 24;
  const int row0 = blockIdx.y * 16, col0 = blockIdx.x * 64;
  const int tx = tid & 15, ty = tid >> 4;
  for (int i = tid; i < OCB * 96 * 9; i += 256) wsh[i] = wgt[ocg * (OCB * 96 * 9) + i];
  float acc[OCB][4];
#pragma unroll
  for (int o = 0; o < OCB; ++o)
#pragma unroll
    for (int p = 0; p < 4; ++p) acc[o][p] = 0.f;
  const float* xb = x + (size_t)b * 96 * 128 * 128;
  for (int ic0 = 0; ic0 < 96; ic0 += ICB) {
    __syncthreads();
    for (int idx = tid; idx < ICB * 18 * 66; idx += 256) {
      int j = idx / (18 * 66), rem = idx - j * (18 * 66);
      int r = rem / 66, c = rem - r * 66;
      int gr = row0 - 1 + r, gc = col0 - 1 + c;
      float v = 0.f;
      if ((unsigned)gr < 128u && (unsigned)gc < 128u)
        v = xb[((size_t)(ic0 + j) * 128 + gr) * 128 + gc];
      patch[j * (18 * PSTRIDE) + r * PSTRIDE + c] = v;
    }
    __syncthreads();
#pragma unroll
    for (int j = 0; j < ICB; ++j) {
      float xr[3][6];
      const float* pp = &patch[j * (18 * PSTRIDE) + ty * PSTRIDE + tx * 4];
#pragma unroll
      for (int dy = 0; dy < 3; ++dy)
#pragma unroll
        for (int dx = 0; dx < 6; ++dx) xr[dy][dx] = pp[dy * PSTRIDE + dx];
#pragma unroll
      for (int o = 0; o < OCB; ++o) {
        const float* wp = &wsh[(o * 96 + ic0 + j) * 9];
#pragma unroll
        for (int p = 0; p < 4; ++p)
          acc[o][p] += wp[0] * xr[0][p] + wp[1] * xr[0][p + 1] + wp[2] * xr[0][p + 2]
                     + wp[3] * xr[1][p] + wp[4] * xr[1][p + 1] + wp[5] * xr[1][p + 2]
                     + wp[6] * xr[2][p] + wp[7] * xr[2][p + 1] + wp[8] * xr[2][p + 2];
      }
    }
  }
  const int h = row0 + ty;
#pragma unroll
  for (int o = 0; o < OCB; ++o) {
    int ocglob = ocg * OCB + o;
    int cq = ocglob >> 2, r2 = (ocglob >> 1) & 1, s2 = ocglob & 1;
    float* orow = y + (((size_t)b * 48 + cq) * 256 + (2 * h + r2)) * 256;
#pragma unroll
    for (int p = 0; p < 4; ++p) orow[2 * (col0 + tx * 4 + p) + s2] = acc[o][p];
  }
}

// ================= wave-synchronous register radix-4 FFT (256 = 4^4) =================
// Forward DIF: k = q + 4*q2 + 16*q3 + 64*q4. Mask k in [64,192) <=> q4 in {1,2}.
__device__ __forceinline__ float2 cadd(float2 a, float2 b){return make_float2(a.x+b.x, a.y+b.y);}
__device__ __forceinline__ float2 csub(float2 a, float2 b){return make_float2(a.x-b.x, a.y-b.y);}
__device__ __forceinline__ float2 cmul(float2 a, float2 b){return make_float2(a.x*b.x-a.y*b.y, a.x*b.y+a.y*b.x);}
__device__ __forceinline__ float2 cmulc(float2 a, float2 b){return make_float2(a.x*b.x+a.y*b.y, a.y*b.x-a.x*b.y);}

__device__ __forceinline__ void dft4(float2 r[4]) {
  float2 e0 = cadd(r[0], r[2]), e1 = csub(r[0], r[2]);
  float2 o0 = cadd(r[1], r[3]), o1 = csub(r[1], r[3]);
  r[0] = cadd(e0, o0);
  r[2] = csub(e0, o0);
  r[1] = make_float2(e1.x + o1.y, e1.y - o1.x);
  r[3] = make_float2(e1.x - o1.y, e1.y + o1.x);
}
__device__ __forceinline__ void idft4(float2 r[4]) {
  float2 e0 = cadd(r[0], r[2]), e1 = csub(r[0], r[2]);
  float2 o0 = cadd(r[1], r[3]), o1 = csub(r[1], r[3]);
  r[0] = cadd(e0, o0);
  r[2] = csub(e0, o0);
  r[1] = make_float2(e1.x - o1.y, e1.y + o1.x);
  r[3] = make_float2(e1.x + o1.y, e1.y - o1.x);
}

struct TwSet {
  float2 f1[3], f2[3], f3[3], i2[4], i3[4];
};

__device__ __forceinline__ void load_tw(TwSet& T, const float2* __restrict__ tw, int l) {
  const int qq = l >> 4, m = l & 15, q2r = (l >> 2) & 3, c2 = l & 3;
  T.f1[0] = tw[l];
  T.f1[1] = tw[(2 * l) & 255];
  T.f1[2] = tw[(3 * l) & 255];
  T.f2[0] = tw[(4 * m) & 255];
  T.f2[1] = tw[(8 * m) & 255];
  T.f2[2] = tw[(12 * m) & 255];
  T.f3[0] = tw[(16 * c2) & 255];
  T.f3[1] = tw[(32 * c2) & 255];
  T.f3[2] = tw[(48 * c2) & 255];
  T.i2[0] = tw[(4 * c2 * q2r) & 255];
  T.i2[1] = tw[(4 * (c2 + 4) * q2r) & 255];
  T.i2[2] = tw[(4 * (c2 + 8) * q2r) & 255];
  T.i2[3] = tw[(4 * (c2 + 12) * q2r) & 255];
  T.i3[0] = tw[(m * qq) & 255];
  T.i3[1] = tw[((m + 16) * qq) & 255];
  T.i3[2] = tw[((m + 32) * qq) & 255];
  T.i3[3] = tw[((m + 48) * qq) & 255];
}

// r[t] in: x[l + 64t]; out: L[l + 64t] (unscaled). S = per-line LDS (element s at S[ST*s]).
template <int ST>
__device__ void fft_line_masked(float2 r[4], float2* __restrict__ S, const TwSet& T, int l) {
  const int qq = l >> 4, m = l & 15;
  const int g = l >> 2, q2r = (l >> 2) & 3, c2 = l & 3;
  // ---- F1 (stride 64) + twiddle w256^(l*q)
  dft4(r);
  r[1] = cmul(r[1], T.f1[0]);
  r[2] = cmul(r[2], T.f1[1]);
  r[3] = cmul(r[3], T.f1[2]);
  S[ST * l] = r[0];
  S[ST * (64 + l)] = r[1];
  S[ST * (128 + l)] = r[2];
  S[ST * (192 + l)] = r[3];
#pragma unroll
  for (int t = 0; t < 4; ++t) r[t] = S[ST * (qq * 64 + m + 16 * t)];
  // ---- F2 (stride 16 within 64) + w64^(m*q2)
  dft4(r);
  r[1] = cmul(r[1], T.f2[0]);
  r[2] = cmul(r[2], T.f2[1]);
  r[3] = cmul(r[3], T.f2[2]);
#pragma unroll
  for (int q2 = 0; q2 < 4; ++q2) S[ST * (qq * 64 + q2 * 16 + ((m + 4 * q2) & 15))] = r[q2];
#pragma unroll
  for (int t = 0; t < 4; ++t) r[t] = S[ST * (qq * 64 + q2r * 16 + ((c2 + 4 * t + 4 * q2r) & 15))];
  // ---- F3 (stride 4 within 16) + w16^(c*q3)
  dft4(r);
  r[1] = cmul(r[1], T.f3[0]);
  r[2] = cmul(r[2], T.f3[1]);
  r[3] = cmul(r[3], T.f3[2]);
#pragma unroll
  for (int q3 = 0; q3 < 4; ++q3) S[ST * (g * 16 + ((4 * q3 + c2 + g) & 15))] = r[q3];
#pragma unroll
  for (int t = 0; t < 4; ++t) r[t] = S[ST * (g * 16 + ((4 * c2 + t + g) & 15))];
  // ---- F4 (final DFT-4) -> regs q4; mask q4 in {1,2}; I1 with 2 nonzero inputs
  dft4(r);
  {
    float2 V0 = r[0], V3 = r[3];
    r[0] = cadd(V0, V3);
    r[1] = make_float2(V0.x + V3.y, V0.y - V3.x);   // V0 + (-i)V3
    r[2] = csub(V0, V3);
    r[3] = make_float2(V0.x - V3.y, V0.y + V3.x);   // V0 + (i)V3
  }
  // undo F3 twiddle (conj), reg index = c, lane q3 = c2
  r[1] = cmulc(r[1], T.f3[0]);
  r[2] = cmulc(r[2], T.f3[1]);
  r[3] = cmulc(r[3], T.f3[2]);
#pragma unroll
  for (int j = 0; j < 4; ++j) S[ST * (g * 16 + ((4 * c2 + j + g) & 15))] = r[j];
#pragma unroll
  for (int t = 0; t < 4; ++t) r[t] = S[ST * (g * 16 + ((4 * t + c2 + g) & 15))];
  // ---- I2 (inverse over q3) -> positions m = c2+4t; undo F2 twiddle
  idft4(r);
  r[0] = cmulc(r[0], T.i2[0]);
  r[1] = cmulc(r[1], T.i2[1]);
  r[2] = cmulc(r[2], T.i2[2]);
  r[3] = cmulc(r[3], T.i2[3]);
#pragma unroll
  for (int t1 = 0; t1 < 4; ++t1) S[ST * (qq * 64 + q2r * 16 + ((c2 + 4 * t1 + 4 * q2r) & 15))] = r[t1];
#pragma unroll
  for (int t = 0; t < 4; ++t) r[t] = S[ST * (qq * 64 + t * 16 + ((m + 4 * t) & 15))];
  // ---- I3 (inverse over q2) -> positions l' = m+16t; undo F1 twiddle
  idft4(r);
  r[0] = cmulc(r[0], T.i3[0]);
  r[1] = cmulc(r[1], T.i3[1]);
  r[2] = cmulc(r[2], T.i3[2]);
  r[3] = cmulc(r[3], T.i3[3]);
#pragma unroll
  for (int t2 = 0; t2 < 4; ++t2) S[ST * (qq * 64 + m + 16 * t2)] = r[t2];
#pragma unroll
  for (int t = 0; t < 4; ++t) r[t] = S[ST * (t * 64 + l)];
  // ---- I4 (inverse over q) -> x[l + 64t]
  idft4(r);
}

// Row pass: 4 lines/block (1 per wave), no barriers in transform
__global__ __launch_bounds__(256)
void fft_rows_kernel(const float* __restrict__ y, float2* __restrict__ z1) {
  __shared__ float2 S[4 * 256];
  __shared__ float2 tw[256];
  const int tid = threadIdx.x;
  {
    float sn, cs;
    __sincosf(-2.f * PI_F * (float)tid / 256.f, &sn, &cs);
    tw[tid] = make_float2(cs, sn);
  }
  __syncthreads();
  const int wv = tid >> 6, l = tid & 63;
  TwSet T;
  load_tw(T, tw, l);
  const size_t rowbase = ((size_t)blockIdx.x * 4 + wv) * 256;
  float2 r[4];
#pragma unroll
  for (int t = 0; t < 4; ++t) r[t] = make_float2(y[rowbase + l + 64 * t], 0.f);
  fft_line_masked<1>(r, S + wv * 256, T, l);
#pragma unroll
  for (int t = 0; t < 4; ++t)
    z1[rowbase + l + 64 * t] = make_float2(r[t].x * (1.f / 256.f), r[t].y * (1.f / 256.f));
}

// Col pass: 16-col strip in LDS (stride 17), in-place FFT per column, 4 cols/wave
#define CST 17
__global__ __launch_bounds__(256)
void fft_cols_kernel(const float2* __restrict__ z1, const float* __restrict__ yy,
                     float* __restrict__ out, const float* __restrict__ betaPtr) {
  __shared__ float2 strip[256 * CST];
  __shared__ float2 tw[256];
  const int tid = threadIdx.x;
  {
    float sn, cs;
    __sincosf(-2.f * PI_F * (float)tid / 256.f, &sn, &cs);
    tw[tid] = make_float2(cs, sn);
  }
  const int img = blockIdx.x >> 4;
  const int c0 = (blockIdx.x & 15) * 16;
  const size_t ibase = (size_t)img * 65536;
#pragma unroll
  for (int it = 0; it < 16; ++it) {
    int idx = it * 256 + tid;
    int rrow = idx >> 4, cc = idx & 15;
    strip[rrow * CST + cc] = z1[ibase + (size_t)rrow * 256 + c0 + cc];
  }
  __syncthreads();
  const int wv = tid >> 6, l = tid & 63;
  TwSet T;
  load_tw(T, tw, l);
  float2 r[4];
#pragma unroll
  for (int ci = 0; ci < 4; ++ci) {
    const int c = wv * 4 + ci;
    float2* Sc = strip + c;
#pragma unroll
    for (int t = 0; t < 4; ++t) r[t] = Sc[CST * (l + 64 * t)];
    fft_line_masked<CST>(r, Sc, T, l);
#pragma unroll
    for (int t = 0; t < 4; ++t) {
      float2 v = r[t];
      Sc[CST * (l + 64 * t)].x = sqrtf(v.x * v.x + v.y * v.y) * (1.f / 256.f);
    }
  }
  __syncthreads();
  const float beta = betaPtr[0];
  const float a1 = 1.f - 2.f * beta;
#pragma unroll
  for (int it = 0; it < 16; ++it) {
    int idx = it * 256 + tid;
    int rrow = idx >> 4, cc = idx & 15;
    size_t gi = ibase + (size_t)rrow * 256 + c0 + cc;
    out[gi] = beta * yy[gi] + a1 * strip[rrow * CST + cc].x;
  }
}

// ================= launch =================
extern "C" void kernel_launch(void* const* d_in, const int* in_sizes, int n_in,
                              void* d_out, int out_size, void* d_ws, size_t ws_size,
                              hipStream_t stream) {
  const float* x = (const float*)d_in[0];
  const float* wgt = (const float*)d_in[1];
  const float* beta = (const float*)d_in[2];
  float* out = (float*)d_out;

  const size_t wplane = (size_t)9 * 192 * 96;
  const size_t wbytes = (2 * wplane * sizeof(unsigned short) + 255) & ~(size_t)255;
  const size_t per_img = 65536ull * sizeof(float2);
  const int NIMG = 8 * 48;

  float2* z1;
  size_t z1_bytes;

  if (ws_size >= wbytes + per_img) {
    unsigned short* whi = (unsigned short*)d_ws;
    unsigned short* wlo = whi + wplane;
    z1 = (float2*)((char*)d_ws + wbytes);
    z1_bytes = ws_size - wbytes;
    prep_w<<<648, 256, 0, stream>>>(wgt, whi, wlo);
    conv_mfma<<<dim3(2, 128, 8), 256, 0, stream>>>(x, whi, wlo, out);
  } else {
    z1 = (float2*)d_ws;
    z1_bytes = ws_size;
    conv_ps_kernel<<<dim3(2, 8, 192), 256, 0, stream>>>(x, wgt, out);
  }

  int chunk = (int)(z1_bytes / per_img);
  if (chunk < 1) chunk = 1;
  if (chunk > NIMG) chunk = NIMG;
  for (int img0 = 0; img0 < NIMG; img0 += chunk) {
    int n = NIMG - img0;
    if (n > chunk) n = chunk;
    float* ych = out + (size_t)img0 * 65536;
    fft_rows_kernel<<<n * 64, 256, 0, stream>>>(ych, z1);
    fft_cols_kernel<<<n * 16, 256, 0, stream>>>(z1, ych, ych, beta);
  }
}